// Round 6
// baseline (4246.679 us; speedup 1.0000x reference)
//
#include <hip/hip_runtime.h>

#define NT 512   // timesteps
#define FB 128   // feature bins
#define HD 256   // L1 == L2 hidden
#define NC 10
#define GR 4     // batch rows per group
#define NG 64    // groups (NG*GR = 256 = batch)

typedef __attribute__((ext_vector_type(8))) short bf16x8;
typedef __attribute__((ext_vector_type(4))) float f32x4;

static __device__ __forceinline__ short f2bf(float f){
  union { float f; unsigned u; } v; v.f = f;
  return (short)((v.u + 0x7fffu + ((v.u >> 16) & 1u)) >> 16);  // RNE
}
static __device__ __forceinline__ float bf2f(short h){
  union { unsigned u; float f; } v; v.u = ((unsigned)(unsigned short)h) << 16;
  return v.f;
}
static __device__ __forceinline__ float quantw(float w){
  return fminf(fmaxf(rintf(w * 8.0f) * 0.125f, -1.0f), 1.0f);  // exact in bf16
}
static __device__ __forceinline__ bf16x8 loadqw8(const float* __restrict__ p){
  bf16x8 v;
#pragma unroll
  for (int j = 0; j < 8; ++j) v[j] = f2bf(quantw(p[j]));
  return v;
}
static __device__ __forceinline__ void split8(f32x4 a, f32x4 b, bf16x8& hi, bf16x8& lo){
  float v0[4] = {a[0],a[1],a[2],a[3]}, v1[4] = {b[0],b[1],b[2],b[3]};
#pragma unroll
  for (int j = 0; j < 4; ++j){
    short h = f2bf(v0[j]); hi[j] = h; lo[j] = f2bf(v0[j] - bf2f(h));
  }
#pragma unroll
  for (int j = 0; j < 4; ++j){
    short h = f2bf(v1[j]); hi[4+j] = h; lo[4+j] = f2bf(v1[j] - bf2f(h));
  }
}

// agent-coherent (sc1) messaging via the memory-side coherent point
static __device__ __forceinline__ void st_sc1_u16(unsigned short* p, unsigned v){
  asm volatile("global_store_short %0, %1, off sc1" :: "v"(p), "v"(v) : "memory");
}
static __device__ __forceinline__ void st_sc1_u32(unsigned* p, unsigned v){
  asm volatile("global_store_dword %0, %1, off sc1" :: "v"(p), "v"(v) : "memory");
}
static __device__ __forceinline__ unsigned ld_sc1_u32(const unsigned* p){
  unsigned v;
  asm volatile("global_load_dword %0, %1, off sc1\n\ts_waitcnt vmcnt(0)"
               : "=v"(v) : "v"(p) : "memory");
  return v;
}
static __device__ __forceinline__ void ld2_sc1_x16(const void* ph, const void* pl, f32x4& h, f32x4& l){
  asm volatile("global_load_dwordx4 %0, %2, off sc1\n\t"
               "global_load_dwordx4 %1, %3, off sc1\n\t"
               "s_waitcnt vmcnt(0)"
               : "=&v"(h), "=&v"(l) : "v"(ph), "v"(pl) : "memory");
}

// 512 blocks x 256 threads, 2 blocks/CU (launch_bounds(256,2) caps VGPR<=256).
// gp = bid>>3 (contiguous 8-block groups -> no co-residency requirement), sb = bid&7.
// Each block: 32 h-dims (slice sb) of W1/W2 for 4 batch rows; blocks sb<4 also own
// the head (L3/L4) for batch row gp*4+sb.
// LDS B-tiles: rows 0-3 = hi(batch row), rows 8-11 = lo -> ONE MFMA covers both
// (C cols n<8 = W*hi(row n), n>=8 = W*lo(row n-8); epilogue sums col r + col r+8).
__global__ __launch_bounds__(256, 2)
void egru_persistent(const float* __restrict__ xg,
                     const float* __restrict__ h1ig, const float* __restrict__ h2ig,
                     const float* __restrict__ W1g, const float* __restrict__ b1g,
                     const float* __restrict__ W2g, const float* __restrict__ b2g,
                     const float* __restrict__ W3g, const float* __restrict__ b3g,
                     const float* __restrict__ W4g, const float* __restrict__ b4g,
                     float* __restrict__ outg, float* __restrict__ wsf)
{
  const int tid = threadIdx.x;
  const int gp  = blockIdx.x >> 3;   // group 0..63
  const int sb  = blockIdx.x & 7;    // slice 0..7
  const int wv  = tid >> 6;          // wave 0..3
  const int ln  = tid & 15;          // MFMA frag m/n index
  const int lk  = (tid >> 4) & 3;    // MFMA frag k-subgroup
  const int rz  = sb * 32;           // slice's h-dim base

  __shared__ __align__(16) short in1[16*384];   // k<128 x(t), k>=128 h1; rows 0-3 hi, 8-11 lo
  __shared__ __align__(16) short in2[16*512];   // k<256 h1(t), k>=256 h2; rows 0-3 hi, 8-11 lo
  __shared__ float a_lds[64][17];
  __shared__ float h1own[32][GR];               // fp32 master of own slice [dim][row]
  __shared__ float h2own[32][GR];
  __shared__ float h3p[128], h3q[128], h3row[128];
  __shared__ float ytmp[16];
  __shared__ float W4L[10*130];
  __shared__ float b1s[64], b2s[64], b3L[128], b4L[10];

  // workspace: 4 bf16 planes [NG][GR][HD] (h1hi,h1lo,h2hi,h2lo) + flags[NG][16]
  unsigned short* wsh = (unsigned short*)wsf;
  unsigned short* h1hi = wsh +             (size_t)gp * (GR*HD);
  unsigned short* h1lo = wsh +  65536    + (size_t)gp * (GR*HD);
  unsigned short* h2hi = wsh + 131072    + (size_t)gp * (GR*HD);
  unsigned short* h2lo = wsh + 196608    + (size_t)gp * (GR*HD);
  unsigned* flags = reinterpret_cast<unsigned*>((char*)wsf + 524288) + gp * 16;

  // ---- resident weight fragments (A-operand; bf16-exact quantized weights) ----
  bf16x8 w1f[12], w2f[16], w3f[2][8];
  {
    const int arow = (wv < 2) ? (rz + wv*16 + ln) : (256 + rz + (wv-2)*16 + ln);
#pragma unroll
    for (int ks = 0; ks < 12; ++ks) w1f[ks] = loadqw8(W1g + arow*384 + ks*32 + lk*8);
#pragma unroll
    for (int ks = 0; ks < 16; ++ks) w2f[ks] = loadqw8(W2g + arow*512 + ks*32 + lk*8);
#pragma unroll
    for (int tl = 0; tl < 2; ++tl)
#pragma unroll
      for (int ks = 0; ks < 8; ++ks)
        w3f[tl][ks] = loadqw8(W3g + (wv*32 + tl*16 + ln)*256 + ks*32 + lk*8);
  }

  if (tid < 64){
    int grow = (tid < 32) ? (rz + tid) : (256 + rz + (tid - 32));
    b1s[tid] = b1g[grow];
    b2s[tid] = b2g[grow];
  }
  if (tid < 128) b3L[tid] = b3g[tid];
  if (tid < 10)  b4L[tid] = b4g[tid];
  for (int i = tid; i < 1280; i += 256)
    W4L[(i >> 7)*130 + (i & 127)] = quantw(W4g[i]);

  // zero B-tiles (garbage rows 4-7/12-15 must not be NaN-prone poison)
  for (int i = tid; i < 16*192; i += 256) ((int*)in1)[i] = 0;
  for (int i = tid; i < 16*256; i += 256) ((int*)in2)[i] = 0;
  __syncthreads();

  if (tid < 128){
    const int ur = tid >> 5, uc = tid & 31;     // row 0..3, 8-dim chunk
    bf16x8 hv, lv;
    const float* p1 = h1ig + (size_t)(gp*GR + ur)*HD + uc*8;
    split8(*(const f32x4*)p1, *(const f32x4*)(p1+4), hv, lv);
    *(bf16x8*)((char*)in1 + ur*768       + ((256 + uc*16) ^ ((ur&7)<<4))) = hv;
    *(bf16x8*)((char*)in1 + (ur+8)*768   + ((256 + uc*16) ^ ((ur&7)<<4))) = lv;
    *(bf16x8*)((char*)in2 + ur*1024      + ((      uc*16) ^ ((ur&7)<<4))) = hv;
    *(bf16x8*)((char*)in2 + (ur+8)*1024  + ((      uc*16) ^ ((ur&7)<<4))) = lv;
    const float* p2 = h2ig + (size_t)(gp*GR + ur)*HD + uc*8;
    split8(*(const f32x4*)p2, *(const f32x4*)(p2+4), hv, lv);
    *(bf16x8*)((char*)in2 + ur*1024      + ((512 + uc*16) ^ ((ur&7)<<4))) = hv;
    *(bf16x8*)((char*)in2 + (ur+8)*1024  + ((512 + uc*16) ^ ((ur&7)<<4))) = lv;
    const int d = tid & 31, r = tid >> 5;       // gate-owner mapping
    h1own[d][r] = h1ig[(size_t)(gp*GR+r)*HD + rz + d];
    h2own[d][r] = h2ig[(size_t)(gp*GR+r)*HD + rz + d];
  }
  const int xr = tid >> 4, xf = tid & 15;
  if (xr < GR){
    const float* px = xg + ((size_t)(gp*GR + xr)*NT + 0)*FB + xf*8;
    bf16x8 hv, lv;
    split8(*(const f32x4*)px, *(const f32x4*)(px+4), hv, lv);
    *(bf16x8*)((char*)in1 + xr*768     + ((xf*16) ^ ((xr&7)<<4))) = hv;
    *(bf16x8*)((char*)in1 + (xr+8)*768 + ((xf*16) ^ ((xr&7)<<4))) = lv;
  }
  __syncthreads();

  // ---- prologue: acc1 = L1(0) (single-MFMA hi|lo) ----
  f32x4 acc1 = {0.f,0.f,0.f,0.f};
#pragma unroll
  for (int ks = 0; ks < 12; ++ks){
    bf16x8 bfr = *(bf16x8*)((char*)in1 + ln*768 + ((ks*64 + lk*16) ^ ((ln&7)<<4)));
    acc1 = __builtin_amdgcn_mfma_f32_16x16x32_bf16(w1f[ks], bfr, acc1, 0, 0, 0);
  }

  for (int t = 0; t < NT; ++t){
    f32x4 xa = {0,0,0,0}, xb = {0,0,0,0};
    const bool pf = ((t+1) < NT) && (xr < GR);
    if (pf){
      const float* px = xg + ((size_t)(gp*GR + xr)*NT + (t+1))*FB + xf*8;
      xa = *(const f32x4*)px; xb = *(const f32x4*)(px+4);
    }

    // ---- A1: finish h1(t) ----
#pragma unroll
    for (int r4 = 0; r4 < 4; ++r4){
      int jsl = wv*16 + lk*4 + r4;             // C/D: row=(lane>>4)*4+reg, col=lane&15
      a_lds[jsl][ln] = acc1[r4] + b1s[jsl];
    }
    __syncthreads();
    if (tid < 128){                            // gate: 32 dims x 4 rows, 1 per thread
      const int d = tid & 31, r = tid >> 5;
      float az = a_lds[d][r]    + a_lds[d][r+8];      // hi-col + lo-col
      float ac = a_lds[32+d][r] + a_lds[32+d][r+8];
      float z  = 0.5f*(az/(1.0f+fabsf(az)) + 1.0f);
      float cd = ac/(1.0f+fabsf(ac));
      float hn = z*h1own[d][r] + (1.0f - z)*cd;
      h1own[d][r] = hn;
      short hb = f2bf(hn);
      short lb = f2bf(hn - bf2f(hb));
      st_sc1_u16(&h1hi[r*HD + rz + d], (unsigned)(unsigned short)hb);
      st_sc1_u16(&h1lo[r*HD + rz + d], (unsigned)(unsigned short)lb);
    }
    asm volatile("s_waitcnt vmcnt(0)" ::: "memory");
    __syncthreads();
    if (tid == 0) st_sc1_u32(&flags[sb], (unsigned)(t+1));

    // ======== A-window ========
    if (pf){
      bf16x8 hv, lv;
      split8(xa, xb, hv, lv);
      *(bf16x8*)((char*)in1 + xr*768     + ((xf*16) ^ ((xr&7)<<4))) = hv;
      *(bf16x8*)((char*)in1 + (xr+8)*768 + ((xf*16) ^ ((xr&7)<<4))) = lv;
    }
    f32x4 acc2 = {0.f,0.f,0.f,0.f};            // L2's h2(t-1) half
#pragma unroll
    for (int ks = 8; ks < 16; ++ks){
      bf16x8 bfr = *(bf16x8*)((char*)in2 + ln*1024 + ((ks*64 + lk*16) ^ ((ln&7)<<4)));
      acc2 = __builtin_amdgcn_mfma_f32_16x16x32_bf16(w2f[ks], bfr, acc2, 0, 0, 0);
    }
    if (t > 0 && sb < GR){                     // head(t-1) for batch row gp*GR+sb
      f32x4 acc3a = {0,0,0,0}, acc3b = {0,0,0,0};
#pragma unroll
      for (int ks = 0; ks < 8; ++ks){
        bf16x8 bfr = *(bf16x8*)((char*)in2 + ln*1024 + ((512 + ks*64 + lk*16) ^ ((ln&7)<<4)));
        acc3a = __builtin_amdgcn_mfma_f32_16x16x32_bf16(w3f[0][ks], bfr, acc3a, 0, 0, 0);
        acc3b = __builtin_amdgcn_mfma_f32_16x16x32_bf16(w3f[1][ks], bfr, acc3b, 0, 0, 0);
      }
      if (ln == sb){
#pragma unroll
        for (int r4 = 0; r4 < 4; ++r4){
          int d0 = wv*32 + lk*4 + r4;
          h3p[d0] = acc3a[r4]; h3p[d0+16] = acc3b[r4];
        }
      }
      if (ln == sb + 8){
#pragma unroll
        for (int r4 = 0; r4 < 4; ++r4){
          int d0 = wv*32 + lk*4 + r4;
          h3q[d0] = acc3a[r4]; h3q[d0+16] = acc3b[r4];
        }
      }
      __syncthreads();
      if (tid < 128) h3row[tid] = fmaxf(h3p[tid] + h3q[tid] + b3L[tid], 0.0f);
      __syncthreads();
      if (wv == 0){                            // L4: 4 lanes per class
        const int l = tid, c = l >> 2, kq = l & 3;
        float p = 0.f;
        if (c < 10){
          const float* wr = &W4L[c*130 + kq*32];
          const float* hr = &h3row[kq*32];
#pragma unroll
          for (int k = 0; k < 32; ++k) p += wr[k]*hr[k];
        }
        p += __shfl_xor(p, 1, 4);
        p += __shfl_xor(p, 2, 4);
        if (c < 10 && kq == 0) ytmp[c] = p + b4L[c];
        asm volatile("s_waitcnt lgkmcnt(0)" ::: "memory");
        float yv = (l < 10) ? ytmp[l] : -INFINITY;
        float mx = yv;
#pragma unroll
        for (int off = 1; off < 16; off <<= 1)
          mx = fmaxf(mx, __shfl_xor(mx, off, 16));
        float ex = (l < 10) ? expf(yv - mx) : 0.0f;
        float sm = ex;
#pragma unroll
        for (int off = 1; off < 16; off <<= 1)
          sm += __shfl_xor(sm, off, 16);
        if (l < 10)
          outg[((size_t)(gp*GR + sb)*NT + (t-1))*NC + l] = yv - (mx + logf(sm));
      }
    }
    // ======== end A-window ========

    if (tid >= 64 && tid < 72)                 // wave-1 polls (wave 0 may still be in L4)
      while (ld_sc1_u32(&flags[tid - 64]) < (unsigned)(t+1)) {}
    __syncthreads();
    if (tid < 128){                            // read h1(t): pre-split planes -> LDS direct
      const int ur = tid >> 5, uc = tid & 31;
      f32x4 hv4, lv4;
      ld2_sc1_x16(&h1hi[ur*HD + uc*8], &h1lo[ur*HD + uc*8], hv4, lv4);
      *(f32x4*)((char*)in1 + ur*768      + ((256 + uc*16) ^ ((ur&7)<<4))) = hv4;
      *(f32x4*)((char*)in1 + (ur+8)*768  + ((256 + uc*16) ^ ((ur&7)<<4))) = lv4;
      *(f32x4*)((char*)in2 + ur*1024     + ((      uc*16) ^ ((ur&7)<<4))) = hv4;
      *(f32x4*)((char*)in2 + (ur+8)*1024 + ((      uc*16) ^ ((ur&7)<<4))) = lv4;
    }
    __syncthreads();

    // ---- B: L2's h1(t) half -> h2(t) ----
#pragma unroll
    for (int ks = 0; ks < 8; ++ks){
      bf16x8 bfr = *(bf16x8*)((char*)in2 + ln*1024 + ((ks*64 + lk*16) ^ ((ln&7)<<4)));
      acc2 = __builtin_amdgcn_mfma_f32_16x16x32_bf16(w2f[ks], bfr, acc2, 0, 0, 0);
    }
#pragma unroll
    for (int r4 = 0; r4 < 4; ++r4){
      int jsl = wv*16 + lk*4 + r4;
      a_lds[jsl][ln] = acc2[r4] + b2s[jsl];
    }
    __syncthreads();
    if (tid < 128){
      const int d = tid & 31, r = tid >> 5;
      float az = a_lds[d][r]    + a_lds[d][r+8];
      float ac = a_lds[32+d][r] + a_lds[32+d][r+8];
      float z  = 0.5f*(az/(1.0f+fabsf(az)) + 1.0f);
      float cd = ac/(1.0f+fabsf(ac));
      float hn = z*h2own[d][r] + (1.0f - z)*cd;
      h2own[d][r] = hn;
      short hb = f2bf(hn);
      short lb = f2bf(hn - bf2f(hb));
      st_sc1_u16(&h2hi[r*HD + rz + d], (unsigned)(unsigned short)hb);
      st_sc1_u16(&h2lo[r*HD + rz + d], (unsigned)(unsigned short)lb);
    }
    asm volatile("s_waitcnt vmcnt(0)" ::: "memory");
    __syncthreads();
    if (tid == 0) st_sc1_u32(&flags[8 + sb], (unsigned)(t+1));

    // ======== B-window: L1(t+1) ========
    if (t + 1 < NT){
      f32x4 a1n = {0.f,0.f,0.f,0.f};
#pragma unroll
      for (int ks = 0; ks < 12; ++ks){
        bf16x8 bfr = *(bf16x8*)((char*)in1 + ln*768 + ((ks*64 + lk*16) ^ ((ln&7)<<4)));
        a1n = __builtin_amdgcn_mfma_f32_16x16x32_bf16(w1f[ks], bfr, a1n, 0, 0, 0);
      }
      acc1 = a1n;
    }
    // ======== end B-window ========

    if (tid >= 64 && tid < 72)
      while (ld_sc1_u32(&flags[8 + (tid - 64)]) < (unsigned)(t+1)) {}
    __syncthreads();
    if (tid < 128){                            // read h2(t) -> in2 k>=256
      const int ur = tid >> 5, uc = tid & 31;
      f32x4 hv4, lv4;
      ld2_sc1_x16(&h2hi[ur*HD + uc*8], &h2lo[ur*HD + uc*8], hv4, lv4);
      *(f32x4*)((char*)in2 + ur*1024     + ((512 + uc*16) ^ ((ur&7)<<4))) = hv4;
      *(f32x4*)((char*)in2 + (ur+8)*1024 + ((512 + uc*16) ^ ((ur&7)<<4))) = lv4;
    }
    __syncthreads();
  }

  // ---- epilogue: head(NT-1) ----
  if (sb < GR){
    f32x4 acc3a = {0,0,0,0}, acc3b = {0,0,0,0};
#pragma unroll
    for (int ks = 0; ks < 8; ++ks){
      bf16x8 bfr = *(bf16x8*)((char*)in2 + ln*1024 + ((512 + ks*64 + lk*16) ^ ((ln&7)<<4)));
      acc3a = __builtin_amdgcn_mfma_f32_16x16x32_bf16(w3f[0][ks], bfr, acc3a, 0, 0, 0);
      acc3b = __builtin_amdgcn_mfma_f32_16x16x32_bf16(w3f[1][ks], bfr, acc3b, 0, 0, 0);
    }
    if (ln == sb){
#pragma unroll
      for (int r4 = 0; r4 < 4; ++r4){
        int d0 = wv*32 + lk*4 + r4;
        h3p[d0] = acc3a[r4]; h3p[d0+16] = acc3b[r4];
      }
    }
    if (ln == sb + 8){
#pragma unroll
      for (int r4 = 0; r4 < 4; ++r4){
        int d0 = wv*32 + lk*4 + r4;
        h3q[d0] = acc3a[r4]; h3q[d0+16] = acc3b[r4];
      }
    }
    __syncthreads();
    if (tid < 128) h3row[tid] = fmaxf(h3p[tid] + h3q[tid] + b3L[tid], 0.0f);
    __syncthreads();
    if (wv == 0){
      const int l = tid, c = l >> 2, kq = l & 3;
      float p = 0.f;
      if (c < 10){
        const float* wr = &W4L[c*130 + kq*32];
        const float* hr = &h3row[kq*32];
#pragma unroll
        for (int k = 0; k < 32; ++k) p += wr[k]*hr[k];
      }
      p += __shfl_xor(p, 1, 4);
      p += __shfl_xor(p, 2, 4);
      if (c < 10 && kq == 0) ytmp[c] = p + b4L[c];
      asm volatile("s_waitcnt lgkmcnt(0)" ::: "memory");
      float yv = (l < 10) ? ytmp[l] : -INFINITY;
      float mx = yv;
#pragma unroll
      for (int off = 1; off < 16; off <<= 1)
        mx = fmaxf(mx, __shfl_xor(mx, off, 16));
      float ex = (l < 10) ? expf(yv - mx) : 0.0f;
      float sm = ex;
#pragma unroll
      for (int off = 1; off < 16; off <<= 1)
        sm += __shfl_xor(sm, off, 16);
      if (l < 10)
        outg[((size_t)(gp*GR + sb)*NT + (NT-1))*NC + l] = yv - (mx + logf(sm));
    }
  }
}

extern "C" void kernel_launch(void* const* d_in, const int* in_sizes, int n_in,
                              void* d_out, int out_size, void* d_ws, size_t ws_size,
                              hipStream_t stream) {
  const float* xg  = (const float*)d_in[0];
  const float* h1i = (const float*)d_in[1];
  const float* h2i = (const float*)d_in[2];
  const float* W1  = (const float*)d_in[3];
  const float* b1  = (const float*)d_in[4];
  const float* W2  = (const float*)d_in[5];
  const float* b2  = (const float*)d_in[6];
  const float* W3  = (const float*)d_in[7];
  const float* b3  = (const float*)d_in[8];
  const float* W4  = (const float*)d_in[9];
  const float* b4  = (const float*)d_in[10];
  float* out = (float*)d_out;
  float* ws  = (float*)d_ws;

  // zero flag words (stream-ordered): planes occupy 512 KiB, flags 4 KiB after
  hipMemsetAsync((char*)d_ws + 524288, 0, NG * 16 * sizeof(unsigned), stream);

  egru_persistent<<<dim3(512), dim3(256), 0, stream>>>(
      xg, h1i, h2i, W1, b1, W2, b2, W3, b3, W4, b4, out, ws);
}

// Round 8
// 2464.932 us; speedup vs baseline: 1.7228x; 1.7228x over previous
//
#include <hip/hip_runtime.h>

#define NT 512   // timesteps
#define FB 128   // feature bins
#define HD 256   // L1 == L2 hidden
#define NC 10
#define NG 32    // groups
#define GR 8     // batch rows per group

typedef __attribute__((ext_vector_type(8))) short bf16x8;
typedef __attribute__((ext_vector_type(4))) float f32x4;

static __device__ __forceinline__ short f2bf(float f){
  union { float f; unsigned u; } v; v.f = f;
  return (short)((v.u + 0x7fffu + ((v.u >> 16) & 1u)) >> 16);  // RNE
}
static __device__ __forceinline__ float bf2f(short h){
  union { unsigned u; float f; } v; v.u = ((unsigned)(unsigned short)h) << 16;
  return v.f;
}
static __device__ __forceinline__ float quantw(float w){
  return fminf(fmaxf(rintf(w * 8.0f) * 0.125f, -1.0f), 1.0f);  // exact in bf16
}
static __device__ __forceinline__ bf16x8 loadqw8(const float* __restrict__ p){
  bf16x8 v;
#pragma unroll
  for (int j = 0; j < 8; ++j) v[j] = f2bf(quantw(p[j]));
  return v;
}
static __device__ __forceinline__ void split8(f32x4 a, f32x4 b, bf16x8& hi, bf16x8& lo){
  float v0[4] = {a[0],a[1],a[2],a[3]}, v1[4] = {b[0],b[1],b[2],b[3]};
#pragma unroll
  for (int j = 0; j < 4; ++j){
    short h = f2bf(v0[j]); hi[j] = h; lo[j] = f2bf(v0[j] - bf2f(h));
  }
#pragma unroll
  for (int j = 0; j < 4; ++j){
    short h = f2bf(v1[j]); hi[4+j] = h; lo[4+j] = f2bf(v1[j] - bf2f(h));
  }
}

// ---- proven R5 sc1 messaging (memory-side coherent point, no cache maintenance) ----
static __device__ __forceinline__ void st1_f32(float* p, float v){
  asm volatile("global_store_dword %0, %1, off sc1" :: "v"(p), "v"(v) : "memory");
}
static __device__ __forceinline__ void st1_u32(unsigned* p, unsigned v){
  asm volatile("global_store_dword %0, %1, off sc1" :: "v"(p), "v"(v) : "memory");
}
static __device__ __forceinline__ unsigned ld1_u32(const unsigned* p){
  unsigned v;
  asm volatile("global_load_dword %0, %1, off sc1\n\ts_waitcnt vmcnt(0)"
               : "=v"(v) : "v"(p) : "memory");
  return v;
}
static __device__ __forceinline__ void ld_x8(const float* p, f32x4& a, f32x4& b){
  asm volatile("global_load_dwordx4 %0, %2, off sc1\n\t"
               "global_load_dwordx4 %1, %2, off offset:16 sc1\n\t"
               "s_waitcnt vmcnt(0)"
               : "=&v"(a), "=&v"(b) : "v"(p) : "memory");
}

// 256 blocks x 256 threads, 1 block/CU. gp = bid&31, sb = bid>>5 (R5 grouping).
// Single-MFMA hi|lo: B-tile rows 0-7 = hi(batch row), 8-15 = lo -> one MFMA gives
// W*hi in C cols 0-7 and W*lo in cols 8-15; gates sum cols r and r+8 (R6-validated).
// Deferred h2 gather (next step's A-window) + double-buffered h1buf/h2buf.
// Per-wave flags: each wave posts after its own vmcnt drain (no producer barrier).
__global__ __launch_bounds__(256, 1)
void egru_persistent(const float* __restrict__ xg,
                     const float* __restrict__ h1ig, const float* __restrict__ h2ig,
                     const float* __restrict__ W1g, const float* __restrict__ b1g,
                     const float* __restrict__ W2g, const float* __restrict__ b2g,
                     const float* __restrict__ W3g, const float* __restrict__ b3g,
                     const float* __restrict__ W4g, const float* __restrict__ b4g,
                     float* __restrict__ outg, float* __restrict__ wsf)
{
  const int tid = threadIdx.x;
  const int gp  = blockIdx.x & 31;   // group 0..31
  const int sb  = blockIdx.x >> 5;   // slice 0..7
  const int wv  = tid >> 6;          // wave 0..3
  const int ln  = tid & 15;          // MFMA frag m/n index
  const int lk  = (tid >> 4) & 3;    // MFMA frag k-subgroup
  const int rz  = sb * 32;           // slice's h-dim base

  __shared__ __align__(16) short in1[16*384];   // k<128 x(t), k>=128 h1; rows 0-7 hi, 8-15 lo
  __shared__ __align__(16) short in2[16*512];   // k<256 h1(t), k>=256 h2; rows 0-7 hi, 8-15 lo
  __shared__ float aldsA[64][17];               // L1 raw MFMA out
  __shared__ float aldsB[64][17];               // L2 raw MFMA out (separate: no WAR across phases)
  __shared__ float h1own[32][GR];               // fp32 master of own slice [dim][row]
  __shared__ float h2own[32][GR];
  __shared__ float h3p[128], h3q[128], h3row[128];
  __shared__ float ytmp[16];
  __shared__ float W4L[10*130];
  __shared__ float b1s[64], b2s[64], b3L[128], b4L[10];

  // workspace layout (floats): h1b[2] @0/+65536, h2b[2] @+131072/+196608,
  // ctrl (u32, memset-zeroed) @ +262144: [NG][64] = flagsA[4][8] | flagsB[4][8]
  float* h1b0 = wsf             + (size_t)gp * (GR*HD);
  float* h1b1 = wsf +  65536    + (size_t)gp * (GR*HD);
  float* h2b0 = wsf + 131072    + (size_t)gp * (GR*HD);
  float* h2b1 = wsf + 196608    + (size_t)gp * (GR*HD);
  unsigned* ctrl   = reinterpret_cast<unsigned*>(wsf + 262144);
  unsigned* flagsA = ctrl + gp * 64;       // 32 words: [wave][slice]
  unsigned* flagsB = flagsA + 32;          // 32 words

  // ---- resident weight fragments (A-operand; quantized weights exact in bf16) ----
  bf16x8 w1f[12], w2f[16], w3f[2][8];
  {
    const int arow = (wv < 2) ? (rz + wv*16 + ln) : (256 + rz + (wv-2)*16 + ln);
#pragma unroll
    for (int ks = 0; ks < 12; ++ks) w1f[ks] = loadqw8(W1g + arow*384 + ks*32 + lk*8);
#pragma unroll
    for (int ks = 0; ks < 16; ++ks) w2f[ks] = loadqw8(W2g + arow*512 + ks*32 + lk*8);
#pragma unroll
    for (int tl = 0; tl < 2; ++tl)
#pragma unroll
      for (int ks = 0; ks < 8; ++ks)
        w3f[tl][ks] = loadqw8(W3g + (wv*32 + tl*16 + ln)*256 + ks*32 + lk*8);
  }

  if (tid < 64){
    int grow = (tid < 32) ? (rz + tid) : (256 + rz + (tid - 32));
    b1s[tid] = b1g[grow];
    b2s[tid] = b2g[grow];
  }
  if (tid < 128) b3L[tid] = b3g[tid];
  if (tid < 10)  b4L[tid] = b4g[tid];
  for (int i = tid; i < 1280; i += 256)
    W4L[(i >> 7)*130 + (i & 127)] = quantw(W4g[i]);

  const int ur = tid >> 5, uc = tid & 31;   // (batch row, 8-dim chunk), 8x32
  const int d_ = tid & 31, r_ = tid >> 5;   // gate mapping: one (dim,row) per thread
  {
    bf16x8 hv, lv;
    const float* p1 = h1ig + (size_t)(gp*GR + ur)*HD + uc*8;
    split8(*(const f32x4*)p1, *(const f32x4*)(p1+4), hv, lv);
    *(bf16x8*)((char*)in1 + ur*768       + ((256 + uc*16) ^ ((ur&7)<<4))) = hv;
    *(bf16x8*)((char*)in1 + (ur+8)*768   + ((256 + uc*16) ^ ((ur&7)<<4))) = lv;
    *(bf16x8*)((char*)in2 + ur*1024      + ((      uc*16) ^ ((ur&7)<<4))) = hv;
    *(bf16x8*)((char*)in2 + (ur+8)*1024  + ((      uc*16) ^ ((ur&7)<<4))) = lv;
    const float* p2 = h2ig + (size_t)(gp*GR + ur)*HD + uc*8;
    split8(*(const f32x4*)p2, *(const f32x4*)(p2+4), hv, lv);
    *(bf16x8*)((char*)in2 + ur*1024      + ((512 + uc*16) ^ ((ur&7)<<4))) = hv;
    *(bf16x8*)((char*)in2 + (ur+8)*1024  + ((512 + uc*16) ^ ((ur&7)<<4))) = lv;
    h1own[d_][r_] = h1ig[(size_t)(gp*GR+r_)*HD + rz + d_];
    h2own[d_][r_] = h2ig[(size_t)(gp*GR+r_)*HD + rz + d_];
  }
  const int xr = tid >> 4, xf = tid & 15;   // x staging (rows >=8 unused)
  if (xr < 8){
    const float* px = xg + ((size_t)(gp*GR + xr)*NT + 0)*FB + xf*8;
    bf16x8 hv, lv;
    split8(*(const f32x4*)px, *(const f32x4*)(px+4), hv, lv);
    *(bf16x8*)((char*)in1 + xr*768     + ((xf*16) ^ ((xr&7)<<4))) = hv;
    *(bf16x8*)((char*)in1 + (xr+8)*768 + ((xf*16) ^ ((xr&7)<<4))) = lv;
  }
  __syncthreads();

  // ---- prologue: acc1 = L1(0) (single MFMA covers hi|lo) ----
  f32x4 acc1 = {0.f,0.f,0.f,0.f};
#pragma unroll
  for (int ks = 0; ks < 12; ++ks){
    bf16x8 bfr = *(bf16x8*)((char*)in1 + ln*768 + ((ks*64 + lk*16) ^ ((ln&7)<<4)));
    acc1 = __builtin_amdgcn_mfma_f32_16x16x32_bf16(w1f[ks], bfr, acc1, 0, 0, 0);
  }

  for (int t = 0; t < NT; ++t){
    float* h1w = (t & 1) ? h1b1 : h1b0;       // write/read slot for h1(t)
    float* h2w = (t & 1) ? h2b1 : h2b0;       // write slot for h2(t)
    float* h2r = (t & 1) ? h2b0 : h2b1;       // read slot for h2(t-1)

    // ---- A1: finish h1(t) from acc1 ----
#pragma unroll
    for (int r4 = 0; r4 < 4; ++r4)
      aldsA[wv*16 + lk*4 + r4][ln] = acc1[r4];   // C/D: row=(lane>>4)*4+reg, col=lane&15
    __syncthreads();                                                   // BAR1
    {
      float az = aldsA[d_][r_]    + aldsA[d_][r_+8]    + b1s[d_];      // hi + lo + bias once
      float ac = aldsA[32+d_][r_] + aldsA[32+d_][r_+8] + b1s[32+d_];
      float z  = 0.5f*(az/(1.0f+fabsf(az)) + 1.0f);
      float cd = ac/(1.0f+fabsf(ac));
      float hn = z*h1own[d_][r_] + (1.0f - z)*cd;
      h1own[d_][r_] = hn;
      st1_f32(&h1w[r_*HD + rz + d_], hn);
    }
    asm volatile("s_waitcnt vmcnt(0)" ::: "memory");                   // own wave's stores done
    if ((tid & 63) == 0) st1_u32(&flagsA[wv*8 + sb], (unsigned)(t+1)); // per-wave post, no barrier

    // x(t+1) prefetch: issue now, consume in A2
    f32x4 xa = {0,0,0,0}, xb = {0,0,0,0};
    const bool pf = ((t+1) < NT) && (xr < 8);
    if (pf){
      const float* px = xg + ((size_t)(gp*GR + xr)*NT + (t+1))*FB + xf*8;
      xa = *(const f32x4*)px; xb = *(const f32x4*)(px+4);
    }

    // ---- A-window: deferred h2(t-1) gather + L2 h2-half + head(t-1) ----
    if (t > 0 && tid < 32)
      while (ld1_u32(&flagsB[tid]) < (unsigned)t) {}                   // flagB(t-1) carries value t
    __syncthreads();                                                   // BAR2
    if (t > 0){
      f32x4 a0, a1;
      ld_x8(&h2r[ur*HD + uc*8], a0, a1);
      bf16x8 hv, lv;
      split8(a0, a1, hv, lv);
      *(bf16x8*)((char*)in2 + ur*1024     + ((512 + uc*16) ^ ((ur&7)<<4))) = hv;
      *(bf16x8*)((char*)in2 + (ur+8)*1024 + ((512 + uc*16) ^ ((ur&7)<<4))) = lv;
    }
    __syncthreads();                                                   // BAR3
    f32x4 acc2 = {0.f,0.f,0.f,0.f};                                    // L2's h2(t-1) half
#pragma unroll
    for (int ks = 8; ks < 16; ++ks){
      bf16x8 bfr = *(bf16x8*)((char*)in2 + ln*1024 + ((ks*64 + lk*16) ^ ((ln&7)<<4)));
      acc2 = __builtin_amdgcn_mfma_f32_16x16x32_bf16(w2f[ks], bfr, acc2, 0, 0, 0);
    }
    if (t > 0){                                                        // head(t-1) for row gp*GR+sb
      f32x4 acc3a = {0,0,0,0}, acc3b = {0,0,0,0};
#pragma unroll
      for (int ks = 0; ks < 8; ++ks){
        bf16x8 bfr = *(bf16x8*)((char*)in2 + ln*1024 + ((512 + ks*64 + lk*16) ^ ((ln&7)<<4)));
        acc3a = __builtin_amdgcn_mfma_f32_16x16x32_bf16(w3f[0][ks], bfr, acc3a, 0, 0, 0);
        acc3b = __builtin_amdgcn_mfma_f32_16x16x32_bf16(w3f[1][ks], bfr, acc3b, 0, 0, 0);
      }
      if (ln == sb){
#pragma unroll
        for (int r4 = 0; r4 < 4; ++r4){
          int d0 = wv*32 + lk*4 + r4;
          h3p[d0] = acc3a[r4]; h3p[d0+16] = acc3b[r4];
        }
      }
      if (ln == sb + 8){
#pragma unroll
        for (int r4 = 0; r4 < 4; ++r4){
          int d0 = wv*32 + lk*4 + r4;
          h3q[d0] = acc3a[r4]; h3q[d0+16] = acc3b[r4];
        }
      }
      __syncthreads();                                                 // BAR4
      if (tid < 128) h3row[tid] = fmaxf(h3p[tid] + h3q[tid] + b3L[tid], 0.0f);
      __syncthreads();                                                 // BAR5
      if (wv == 0){                                                    // L4: 4 lanes per class
        const int l = tid, c = l >> 2, kq = l & 3;
        float p = 0.f;
        if (c < 10){
          const float* wr = &W4L[c*130 + kq*32];
          const float* hr = &h3row[kq*32];
#pragma unroll
          for (int k = 0; k < 32; ++k) p += wr[k]*hr[k];
        }
        p += __shfl_xor(p, 1, 4);
        p += __shfl_xor(p, 2, 4);
        if (c < 10 && kq == 0) ytmp[c] = p + b4L[c];
        asm volatile("s_waitcnt lgkmcnt(0)" ::: "memory");
        float yv = (l < 10) ? ytmp[l] : -INFINITY;
        float mx = yv;
#pragma unroll
        for (int off = 1; off < 16; off <<= 1)
          mx = fmaxf(mx, __shfl_xor(mx, off, 16));
        float ex = (l < 10) ? expf(yv - mx) : 0.0f;
        float sm = ex;
#pragma unroll
        for (int off = 1; off < 16; off <<= 1)
          sm += __shfl_xor(sm, off, 16);
        if (l < 10)
          outg[((size_t)(gp*GR + sb)*NT + (t-1))*NC + l] = yv - (mx + logf(sm));
      }
    }

    // ---- A2: h1(t) gather (poll on wave1, overlaps wave0's L4) ----
    if (tid >= 64 && tid < 96)
      while (ld1_u32(&flagsA[tid - 64]) < (unsigned)(t+1)) {}
    __syncthreads();                                                   // BAR6
    {
      f32x4 a0, a1;
      ld_x8(&h1w[ur*HD + uc*8], a0, a1);
      bf16x8 hv, lv;
      split8(a0, a1, hv, lv);
      *(bf16x8*)((char*)in1 + ur*768      + ((256 + uc*16) ^ ((ur&7)<<4))) = hv;
      *(bf16x8*)((char*)in1 + (ur+8)*768  + ((256 + uc*16) ^ ((ur&7)<<4))) = lv;
      *(bf16x8*)((char*)in2 + ur*1024     + ((      uc*16) ^ ((ur&7)<<4))) = hv;
      *(bf16x8*)((char*)in2 + (ur+8)*1024 + ((      uc*16) ^ ((ur&7)<<4))) = lv;
    }
    if (pf){  // x loads complete (ld_x8 drained vmcnt); stage x(t+1)
      bf16x8 hv, lv;
      split8(xa, xb, hv, lv);
      *(bf16x8*)((char*)in1 + xr*768     + ((xf*16) ^ ((xr&7)<<4))) = hv;
      *(bf16x8*)((char*)in1 + (xr+8)*768 + ((xf*16) ^ ((xr&7)<<4))) = lv;
    }
    __syncthreads();                                                   // BAR7

    // ---- B: L2's h1(t) half -> h2(t) ----
#pragma unroll
    for (int ks = 0; ks < 8; ++ks){
      bf16x8 bfr = *(bf16x8*)((char*)in2 + ln*1024 + ((ks*64 + lk*16) ^ ((ln&7)<<4)));
      acc2 = __builtin_amdgcn_mfma_f32_16x16x32_bf16(w2f[ks], bfr, acc2, 0, 0, 0);
    }
#pragma unroll
    for (int r4 = 0; r4 < 4; ++r4)
      aldsB[wv*16 + lk*4 + r4][ln] = acc2[r4];
    __syncthreads();                                                   // BAR8
    {
      float az = aldsB[d_][r_]    + aldsB[d_][r_+8]    + b2s[d_];
      float ac = aldsB[32+d_][r_] + aldsB[32+d_][r_+8] + b2s[32+d_];
      float z  = 0.5f*(az/(1.0f+fabsf(az)) + 1.0f);
      float cd = ac/(1.0f+fabsf(ac));
      float hn = z*h2own[d_][r_] + (1.0f - z)*cd;
      h2own[d_][r_] = hn;
      st1_f32(&h2w[r_*HD + rz + d_], hn);
    }
    asm volatile("s_waitcnt vmcnt(0)" ::: "memory");
    if ((tid & 63) == 0) st1_u32(&flagsB[wv*8 + sb], (unsigned)(t+1));

    // ---- B-window: L1(t+1) ----
    if (t + 1 < NT){
      f32x4 a1n = {0.f,0.f,0.f,0.f};
#pragma unroll
      for (int ks = 0; ks < 12; ++ks){
        bf16x8 bfr = *(bf16x8*)((char*)in1 + ln*768 + ((ks*64 + lk*16) ^ ((ln&7)<<4)));
        a1n = __builtin_amdgcn_mfma_f32_16x16x32_bf16(w1f[ks], bfr, a1n, 0, 0, 0);
      }
      acc1 = a1n;
    }
  }

  // ---- epilogue: gather h2(NT-1), head(NT-1) ----
  if (tid < 32)
    while (ld1_u32(&flagsB[tid]) < (unsigned)NT) {}
  __syncthreads();
  {
    float* h2r = ((NT-1) & 1) ? h2b1 : h2b0;
    f32x4 a0, a1;
    ld_x8(&h2r[ur*HD + uc*8], a0, a1);
    bf16x8 hv, lv;
    split8(a0, a1, hv, lv);
    *(bf16x8*)((char*)in2 + ur*1024     + ((512 + uc*16) ^ ((ur&7)<<4))) = hv;
    *(bf16x8*)((char*)in2 + (ur+8)*1024 + ((512 + uc*16) ^ ((ur&7)<<4))) = lv;
  }
  __syncthreads();
  {
    f32x4 acc3a = {0,0,0,0}, acc3b = {0,0,0,0};
#pragma unroll
    for (int ks = 0; ks < 8; ++ks){
      bf16x8 bfr = *(bf16x8*)((char*)in2 + ln*1024 + ((512 + ks*64 + lk*16) ^ ((ln&7)<<4)));
      acc3a = __builtin_amdgcn_mfma_f32_16x16x32_bf16(w3f[0][ks], bfr, acc3a, 0, 0, 0);
      acc3b = __builtin_amdgcn_mfma_f32_16x16x32_bf16(w3f[1][ks], bfr, acc3b, 0, 0, 0);
    }
    if (ln == sb){
#pragma unroll
      for (int r4 = 0; r4 < 4; ++r4){
        int d0 = wv*32 + lk*4 + r4;
        h3p[d0] = acc3a[r4]; h3p[d0+16] = acc3b[r4];
      }
    }
    if (ln == sb + 8){
#pragma unroll
      for (int r4 = 0; r4 < 4; ++r4){
        int d0 = wv*32 + lk*4 + r4;
        h3q[d0] = acc3a[r4]; h3q[d0+16] = acc3b[r4];
      }
    }
    __syncthreads();
    if (tid < 128) h3row[tid] = fmaxf(h3p[tid] + h3q[tid] + b3L[tid], 0.0f);
    __syncthreads();
    if (wv == 0){
      const int l = tid, c = l >> 2, kq = l & 3;
      float p = 0.f;
      if (c < 10){
        const float* wr = &W4L[c*130 + kq*32];
        const float* hr = &h3row[kq*32];
#pragma unroll
        for (int k = 0; k < 32; ++k) p += wr[k]*hr[k];
      }
      p += __shfl_xor(p, 1, 4);
      p += __shfl_xor(p, 2, 4);
      if (c < 10 && kq == 0) ytmp[c] = p + b4L[c];
      asm volatile("s_waitcnt lgkmcnt(0)" ::: "memory");
      float yv = (l < 10) ? ytmp[l] : -INFINITY;
      float mx = yv;
#pragma unroll
      for (int off = 1; off < 16; off <<= 1)
        mx = fmaxf(mx, __shfl_xor(mx, off, 16));
      float ex = (l < 10) ? expf(yv - mx) : 0.0f;
      float sm = ex;
#pragma unroll
      for (int off = 1; off < 16; off <<= 1)
        sm += __shfl_xor(sm, off, 16);
      if (l < 10)
        outg[((size_t)(gp*GR + sb)*NT + (NT-1))*NC + l] = yv - (mx + logf(sm));
    }
  }
}

extern "C" void kernel_launch(void* const* d_in, const int* in_sizes, int n_in,
                              void* d_out, int out_size, void* d_ws, size_t ws_size,
                              hipStream_t stream) {
  const float* xg  = (const float*)d_in[0];
  const float* h1i = (const float*)d_in[1];
  const float* h2i = (const float*)d_in[2];
  const float* W1  = (const float*)d_in[3];
  const float* b1  = (const float*)d_in[4];
  const float* W2  = (const float*)d_in[5];
  const float* b2  = (const float*)d_in[6];
  const float* W3  = (const float*)d_in[7];
  const float* b3  = (const float*)d_in[8];
  const float* W4  = (const float*)d_in[9];
  const float* b4  = (const float*)d_in[10];
  float* out = (float*)d_out;
  float* ws  = (float*)d_ws;

  // zero the flag region (stream-ordered, completes before the kernel starts)
  // layout: 4 x 256KB h buffers, then ctrl @ 1 MiB (32 groups x 64 u32 = 8 KiB)
  hipMemsetAsync((char*)d_ws + 1048576, 0, 8192, stream);

  egru_persistent<<<dim3(256), dim3(256), 0, stream>>>(
      xg, h1i, h2i, W1, b1, W2, b2, W3, b3, W4, b4, out, ws);
}

// Round 9
// 1903.763 us; speedup vs baseline: 2.2307x; 1.2948x over previous
//
#include <hip/hip_runtime.h>

#define NT 512   // timesteps
#define FB 128   // feature bins
#define HD 256   // L1 == L2 hidden
#define NC 10
#define NG 32    // groups
#define GR 8     // batch rows per group

typedef __attribute__((ext_vector_type(8))) short bf16x8;
typedef __attribute__((ext_vector_type(4))) float f32x4;
typedef __attribute__((ext_vector_type(4))) unsigned u32x4;
typedef __attribute__((ext_vector_type(2))) unsigned u32x2;

static __device__ __forceinline__ short f2bf(float f){
  union { float f; unsigned u; } v; v.f = f;
  return (short)((v.u + 0x7fffu + ((v.u >> 16) & 1u)) >> 16);  // RNE
}
static __device__ __forceinline__ float bf2f(short h){
  union { unsigned u; float f; } v; v.u = ((unsigned)(unsigned short)h) << 16;
  return v.f;
}
static __device__ __forceinline__ float quantw(float w){
  return fminf(fmaxf(rintf(w * 8.0f) * 0.125f, -1.0f), 1.0f);  // exact in bf16
}
static __device__ __forceinline__ bf16x8 loadqw8(const float* __restrict__ p){
  bf16x8 v;
#pragma unroll
  for (int j = 0; j < 8; ++j) v[j] = f2bf(quantw(p[j]));
  return v;
}
static __device__ __forceinline__ void split8(f32x4 a, f32x4 b, bf16x8& hi, bf16x8& lo){
  float v0[4] = {a[0],a[1],a[2],a[3]}, v1[4] = {b[0],b[1],b[2],b[3]};
#pragma unroll
  for (int j = 0; j < 4; ++j){
    short h = f2bf(v0[j]); hi[j] = h; lo[j] = f2bf(v0[j] - bf2f(h));
  }
#pragma unroll
  for (int j = 0; j < 4; ++j){
    short h = f2bf(v1[j]); hi[4+j] = h; lo[4+j] = f2bf(v1[j] - bf2f(h));
  }
}

// ---- epoch-in-band messaging over sc1 (memory-side coherent point) ----
// element = 2 u32 words: (hi_bf16<<16)|epoch, (lo_bf16<<16)|epoch.
// Word-atomic visibility: epoch match in a word guarantees its payload.
// No flags, no producer drains, no separate polls.
static __device__ __forceinline__ void st_msg(unsigned* p, short hb, short lb, unsigned ep){
  u32x2 w;
  w[0] = (((unsigned)(unsigned short)hb) << 16) | ep;
  w[1] = (((unsigned)(unsigned short)lb) << 16) | ep;
  asm volatile("global_store_dwordx2 %0, %1, off sc1" :: "v"(p), "v"(w) : "memory");
}
// gather 8 elements (64 B), retry until all 16 epoch fields match
static __device__ __forceinline__ void gather8(const unsigned* p, unsigned ep, bf16x8& hv, bf16x8& lv){
  u32x4 a, b, c, d;
  for (;;){
    asm volatile("global_load_dwordx4 %0, %4, off sc1\n\t"
                 "global_load_dwordx4 %1, %4, off offset:16 sc1\n\t"
                 "global_load_dwordx4 %2, %4, off offset:32 sc1\n\t"
                 "global_load_dwordx4 %3, %4, off offset:48 sc1\n\t"
                 "s_waitcnt vmcnt(0)"
                 : "=&v"(a), "=&v"(b), "=&v"(c), "=&v"(d) : "v"(p) : "memory");
    unsigned m = (a[0]^ep)|(a[1]^ep)|(a[2]^ep)|(a[3]^ep)
               | (b[0]^ep)|(b[1]^ep)|(b[2]^ep)|(b[3]^ep)
               | (c[0]^ep)|(c[1]^ep)|(c[2]^ep)|(c[3]^ep)
               | (d[0]^ep)|(d[1]^ep)|(d[2]^ep)|(d[3]^ep);
    if ((m & 0xffffu) == 0u) break;
  }
  hv[0]=(short)(a[0]>>16); lv[0]=(short)(a[1]>>16);
  hv[1]=(short)(a[2]>>16); lv[1]=(short)(a[3]>>16);
  hv[2]=(short)(b[0]>>16); lv[2]=(short)(b[1]>>16);
  hv[3]=(short)(b[2]>>16); lv[3]=(short)(b[3]>>16);
  hv[4]=(short)(c[0]>>16); lv[4]=(short)(c[1]>>16);
  hv[5]=(short)(c[2]>>16); lv[5]=(short)(c[3]>>16);
  hv[6]=(short)(d[0]>>16); lv[6]=(short)(d[1]>>16);
  hv[7]=(short)(d[2]>>16); lv[7]=(short)(d[3]>>16);
}

// 256 blocks x 256 threads, 1 block/CU. gp = bid&31, sb = bid>>5.
// Single-MFMA hi|lo (R6-validated); epoch-fused exchange (this round);
// deferred h2 gather + double-buffered slots (R8-validated, 2 slots, induction
// via epoch observation replaces the flag chain).
__global__ __launch_bounds__(256, 1)
void egru_persistent(const float* __restrict__ xg,
                     const float* __restrict__ h1ig, const float* __restrict__ h2ig,
                     const float* __restrict__ W1g, const float* __restrict__ b1g,
                     const float* __restrict__ W2g, const float* __restrict__ b2g,
                     const float* __restrict__ W3g, const float* __restrict__ b3g,
                     const float* __restrict__ W4g, const float* __restrict__ b4g,
                     float* __restrict__ outg, float* __restrict__ wsf)
{
  const int tid = threadIdx.x;
  const int gp  = blockIdx.x & 31;   // group 0..31
  const int sb  = blockIdx.x >> 5;   // slice 0..7
  const int wv  = tid >> 6;          // wave 0..3
  const int ln  = tid & 15;          // MFMA frag m/n index
  const int lk  = (tid >> 4) & 3;    // MFMA frag k-subgroup
  const int rz  = sb * 32;           // slice's h-dim base
  const int lnl = 8 + (ln & 7);      // row for lo-part B reads

  __shared__ __align__(16) short in1[16*384];   // k<128 x(t), k>=128 h1; rows 0-7 hi, 8-15 lo
  __shared__ __align__(16) short in2[16*512];   // k<256 h1(t), k>=256 h2; rows 0-7 hi, 8-15 lo
  __shared__ float aldsA[64][17];               // L1 raw MFMA out
  __shared__ float aldsB[64][17];               // L2 raw MFMA out
  __shared__ float h1own[32][GR];               // fp32 master of own slice [dim][row]
  __shared__ float h2own[32][GR];
  __shared__ float h3p[128], h3q[128], h3row[128];
  __shared__ float ytmp[16];
  __shared__ float W4L[10*130];
  __shared__ float b1s[64], b2s[64], b3L[128], b4L[10];

  // workspace (u32): h1buf 2 slots x [NG][GR][HD] x 2 words @0 (1 MiB),
  //                  h2buf 2 slots @ +262144 u32 (1 MiB). memset-zeroed per launch.
  unsigned* h1buf = reinterpret_cast<unsigned*>(wsf);
  unsigned* h2buf = h1buf + 262144;

  // ---- resident weight fragments (A-operand; quantized weights exact in bf16) ----
  bf16x8 w1f[12], w2f[16], w3f[2][8];
  {
    const int arow = (wv < 2) ? (rz + wv*16 + ln) : (256 + rz + (wv-2)*16 + ln);
#pragma unroll
    for (int ks = 0; ks < 12; ++ks) w1f[ks] = loadqw8(W1g + arow*384 + ks*32 + lk*8);
#pragma unroll
    for (int ks = 0; ks < 16; ++ks) w2f[ks] = loadqw8(W2g + arow*512 + ks*32 + lk*8);
#pragma unroll
    for (int tl = 0; tl < 2; ++tl)
#pragma unroll
      for (int ks = 0; ks < 8; ++ks)
        w3f[tl][ks] = loadqw8(W3g + (wv*32 + tl*16 + ln)*256 + ks*32 + lk*8);
  }

  if (tid < 64){
    int grow = (tid < 32) ? (rz + tid) : (256 + rz + (tid - 32));
    b1s[tid] = b1g[grow];
    b2s[tid] = b2g[grow];
  }
  if (tid < 128) b3L[tid] = b3g[tid];
  if (tid < 10)  b4L[tid] = b4g[tid];
  for (int i = tid; i < 1280; i += 256)
    W4L[(i >> 7)*130 + (i & 127)] = quantw(W4g[i]);

  const int ur = tid >> 5, uc = tid & 31;   // (batch row, dim-chunk/dim) mapping, 8x32
  {
    bf16x8 hv, lv;
    const float* p1 = h1ig + (size_t)(gp*GR + ur)*HD + uc*8;
    split8(*(const f32x4*)p1, *(const f32x4*)(p1+4), hv, lv);
    *(bf16x8*)((char*)in1 + ur*768       + ((256 + uc*16) ^ ((ur&7)<<4))) = hv;
    *(bf16x8*)((char*)in1 + (ur+8)*768   + ((256 + uc*16) ^ ((ur&7)<<4))) = lv;
    *(bf16x8*)((char*)in2 + ur*1024      + ((      uc*16) ^ ((ur&7)<<4))) = hv;
    *(bf16x8*)((char*)in2 + (ur+8)*1024  + ((      uc*16) ^ ((ur&7)<<4))) = lv;
    const float* p2 = h2ig + (size_t)(gp*GR + ur)*HD + uc*8;
    split8(*(const f32x4*)p2, *(const f32x4*)(p2+4), hv, lv);
    *(bf16x8*)((char*)in2 + ur*1024      + ((512 + uc*16) ^ ((ur&7)<<4))) = hv;
    *(bf16x8*)((char*)in2 + (ur+8)*1024  + ((512 + uc*16) ^ ((ur&7)<<4))) = lv;
    h1own[uc][ur] = h1ig[(size_t)(gp*GR+ur)*HD + rz + uc];
    h2own[uc][ur] = h2ig[(size_t)(gp*GR+ur)*HD + rz + uc];
  }
  const int xr = tid >> 4, xf = tid & 15;   // x staging (rows >=8 unused)
  if (xr < 8){
    const float* px = xg + ((size_t)(gp*GR + xr)*NT + 0)*FB + xf*8;
    bf16x8 hv, lv;
    split8(*(const f32x4*)px, *(const f32x4*)(px+4), hv, lv);
    *(bf16x8*)((char*)in1 + xr*768     + ((xf*16) ^ ((xr&7)<<4))) = hv;
    *(bf16x8*)((char*)in1 + (xr+8)*768 + ((xf*16) ^ ((xr&7)<<4))) = lv;
  }
  __syncthreads();

  // ---- prologue: acc1 = L1(0) (single MFMA covers hi|lo) ----
  f32x4 acc1 = {0.f,0.f,0.f,0.f};
#pragma unroll
  for (int ks = 0; ks < 12; ++ks){
    bf16x8 bfr = *(bf16x8*)((char*)in1 + ln*768 + ((ks*64 + lk*16) ^ ((ln&7)<<4)));
    acc1 = __builtin_amdgcn_mfma_f32_16x16x32_bf16(w1f[ks], bfr, acc1, 0, 0, 0);
  }

  for (int t = 0; t < NT; ++t){
    unsigned* h1s = h1buf + (unsigned)(t & 1)*131072u + (unsigned)(gp*GR)*512u;     // write+read h1(t)
    unsigned* h2s = h2buf + (unsigned)(t & 1)*131072u + (unsigned)(gp*GR)*512u;     // write h2(t)
    unsigned* h2r = h2buf + (unsigned)((t + 1) & 1)*131072u + (unsigned)(gp*GR)*512u; // read h2(t-1)

    // ---- A1: finish h1(t); pack + store with epoch t+1 (no drain, no flag) ----
#pragma unroll
    for (int r4 = 0; r4 < 4; ++r4)
      aldsA[wv*16 + lk*4 + r4][ln] = acc1[r4];     // C/D: row=(lane>>4)*4+reg, col=lane&15
    __syncthreads();                                                   // BAR1
    {
      float az = aldsA[uc][ur]    + aldsA[uc][ur+8]    + b1s[uc];      // hi-col + lo-col + bias
      float ac = aldsA[32+uc][ur] + aldsA[32+uc][ur+8] + b1s[32+uc];
      float z  = 0.5f*(az/(1.0f+fabsf(az)) + 1.0f);
      float cd = ac/(1.0f+fabsf(ac));
      float hn = z*h1own[uc][ur] + (1.0f - z)*cd;
      h1own[uc][ur] = hn;
      short hb = f2bf(hn), lb = f2bf(hn - bf2f(hb));
      st_msg(&h1s[ur*512 + (rz + uc)*2], hb, lb, (unsigned)(t+1));
    }

    // x(t+1) prefetch (plain cached loads; staged below)
    f32x4 xa = {0,0,0,0}, xb = {0,0,0,0};
    const bool pf = ((t+1) < NT) && (xr < 8);
    if (pf){
      const float* px = xg + ((size_t)(gp*GR + xr)*NT + (t+1))*FB + xf*8;
      xa = *(const f32x4*)px; xb = *(const f32x4*)(px+4);
    }

    // ---- A-window: gather h2(t-1) (epoch t) + stage x(t+1) ----
    if (t > 0){
      bf16x8 hv, lv;
      gather8(&h2r[ur*512 + uc*16], (unsigned)t, hv, lv);
      *(bf16x8*)((char*)in2 + ur*1024     + ((512 + uc*16) ^ ((ur&7)<<4))) = hv;
      *(bf16x8*)((char*)in2 + (ur+8)*1024 + ((512 + uc*16) ^ ((ur&7)<<4))) = lv;
    }
    if (pf){
      bf16x8 hv, lv;
      split8(xa, xb, hv, lv);
      *(bf16x8*)((char*)in1 + xr*768     + ((xf*16) ^ ((xr&7)<<4))) = hv;
      *(bf16x8*)((char*)in1 + (xr+8)*768 + ((xf*16) ^ ((xr&7)<<4))) = lv;
    }
    __syncthreads();                                                   // BAR3

    // L2's h2(t-1) half
    f32x4 acc2 = {0.f,0.f,0.f,0.f};
#pragma unroll
    for (int ks = 8; ks < 16; ++ks){
      bf16x8 bfr = *(bf16x8*)((char*)in2 + ln*1024 + ((ks*64 + lk*16) ^ ((ln&7)<<4)));
      acc2 = __builtin_amdgcn_mfma_f32_16x16x32_bf16(w2f[ks], bfr, acc2, 0, 0, 0);
    }
    // head(t-1) for batch row gp*GR+sb
    if (t > 0){
      f32x4 acc3a = {0,0,0,0}, acc3b = {0,0,0,0};
#pragma unroll
      for (int ks = 0; ks < 8; ++ks){
        bf16x8 bfr = *(bf16x8*)((char*)in2 + ln*1024 + ((512 + ks*64 + lk*16) ^ ((ln&7)<<4)));
        acc3a = __builtin_amdgcn_mfma_f32_16x16x32_bf16(w3f[0][ks], bfr, acc3a, 0, 0, 0);
        acc3b = __builtin_amdgcn_mfma_f32_16x16x32_bf16(w3f[1][ks], bfr, acc3b, 0, 0, 0);
      }
      if (ln == sb){
#pragma unroll
        for (int r4 = 0; r4 < 4; ++r4){
          int d0 = wv*32 + lk*4 + r4;
          h3p[d0] = acc3a[r4]; h3p[d0+16] = acc3b[r4];
        }
      }
      if (ln == sb + 8){
#pragma unroll
        for (int r4 = 0; r4 < 4; ++r4){
          int d0 = wv*32 + lk*4 + r4;
          h3q[d0] = acc3a[r4]; h3q[d0+16] = acc3b[r4];
        }
      }
      __syncthreads();                                                 // BAR4
      if (tid < 128) h3row[tid] = fmaxf(h3p[tid] + h3q[tid] + b3L[tid], 0.0f);
      __syncthreads();                                                 // BAR5
      if (wv == 0){                                                    // L4: 4 lanes per class
        const int l = tid, c = l >> 2, kq = l & 3;
        float p = 0.f;
        if (c < 10){
          const float* wr = &W4L[c*130 + kq*32];
          const float* hr = &h3row[kq*32];
#pragma unroll
          for (int k = 0; k < 32; ++k) p += wr[k]*hr[k];
        }
        p += __shfl_xor(p, 1, 4);
        p += __shfl_xor(p, 2, 4);
        if (c < 10 && kq == 0) ytmp[c] = p + b4L[c];
        asm volatile("s_waitcnt lgkmcnt(0)" ::: "memory");
        float yv = (l < 10) ? ytmp[l] : -INFINITY;
        float mx = yv;
#pragma unroll
        for (int off = 1; off < 16; off <<= 1)
          mx = fmaxf(mx, __shfl_xor(mx, off, 16));
        float ex = (l < 10) ? expf(yv - mx) : 0.0f;
        float sm = ex;
#pragma unroll
        for (int off = 1; off < 16; off <<= 1)
          sm += __shfl_xor(sm, off, 16);
        if (l < 10)
          outg[((size_t)(gp*GR + sb)*NT + (t-1))*NC + l] = yv - (mx + logf(sm));
      }
    }

    // ---- A2: gather h1(t) (epoch t+1) -> in1 k>=128, in2 k<256 ----
    {
      bf16x8 hv, lv;
      gather8(&h1s[ur*512 + uc*16], (unsigned)(t+1), hv, lv);
      *(bf16x8*)((char*)in1 + ur*768      + ((256 + uc*16) ^ ((ur&7)<<4))) = hv;
      *(bf16x8*)((char*)in1 + (ur+8)*768  + ((256 + uc*16) ^ ((ur&7)<<4))) = lv;
      *(bf16x8*)((char*)in2 + ur*1024     + ((      uc*16) ^ ((ur&7)<<4))) = hv;
      *(bf16x8*)((char*)in2 + (ur+8)*1024 + ((      uc*16) ^ ((ur&7)<<4))) = lv;
    }
    __syncthreads();                                                   // BAR7

    // ---- B: L2's h1(t) half -> h2(t) ----
#pragma unroll
    for (int ks = 0; ks < 8; ++ks){
      bf16x8 bfr = *(bf16x8*)((char*)in2 + ln*1024 + ((ks*64 + lk*16) ^ ((ln&7)<<4)));
      acc2 = __builtin_amdgcn_mfma_f32_16x16x32_bf16(w2f[ks], bfr, acc2, 0, 0, 0);
    }
#pragma unroll
    for (int r4 = 0; r4 < 4; ++r4)
      aldsB[wv*16 + lk*4 + r4][ln] = acc2[r4];
    __syncthreads();                                                   // BAR8
    {
      float az = aldsB[uc][ur]    + aldsB[uc][ur+8]    + b2s[uc];
      float ac = aldsB[32+uc][ur] + aldsB[32+uc][ur+8] + b2s[32+uc];
      float z  = 0.5f*(az/(1.0f+fabsf(az)) + 1.0f);
      float cd = ac/(1.0f+fabsf(ac));
      float hn = z*h2own[uc][ur] + (1.0f - z)*cd;
      h2own[uc][ur] = hn;
      short hb = f2bf(hn), lb = f2bf(hn - bf2f(hb));
      st_msg(&h2s[ur*512 + (rz + uc)*2], hb, lb, (unsigned)(t+1));
    }
    // h2(t) gather deferred to next step's A-window (epoch validates)

    // ---- B-window: L1(t+1) ----
    if (t + 1 < NT){
      f32x4 a1n = {0.f,0.f,0.f,0.f};
#pragma unroll
      for (int ks = 0; ks < 12; ++ks){
        bf16x8 bfr = *(bf16x8*)((char*)in1 + ln*768 + ((ks*64 + lk*16) ^ ((ln&7)<<4)));
        a1n = __builtin_amdgcn_mfma_f32_16x16x32_bf16(w1f[ks], bfr, a1n, 0, 0, 0);
      }
      acc1 = a1n;
    }
  }

  // ---- epilogue: gather h2(NT-1) (epoch NT), head(NT-1) ----
  {
    unsigned* h2e = h2buf + (unsigned)((NT-1) & 1)*131072u + (unsigned)(gp*GR)*512u;
    bf16x8 hv, lv;
    gather8(&h2e[ur*512 + uc*16], (unsigned)NT, hv, lv);
    *(bf16x8*)((char*)in2 + ur*1024     + ((512 + uc*16) ^ ((ur&7)<<4))) = hv;
    *(bf16x8*)((char*)in2 + (ur+8)*1024 + ((512 + uc*16) ^ ((ur&7)<<4))) = lv;
  }
  __syncthreads();
  {
    f32x4 acc3a = {0,0,0,0}, acc3b = {0,0,0,0};
#pragma unroll
    for (int ks = 0; ks < 8; ++ks){
      bf16x8 bfr = *(bf16x8*)((char*)in2 + ln*1024 + ((512 + ks*64 + lk*16) ^ ((ln&7)<<4)));
      acc3a = __builtin_amdgcn_mfma_f32_16x16x32_bf16(w3f[0][ks], bfr, acc3a, 0, 0, 0);
      acc3b = __builtin_amdgcn_mfma_f32_16x16x32_bf16(w3f[1][ks], bfr, acc3b, 0, 0, 0);
    }
    if (ln == sb){
#pragma unroll
      for (int r4 = 0; r4 < 4; ++r4){
        int d0 = wv*32 + lk*4 + r4;
        h3p[d0] = acc3a[r4]; h3p[d0+16] = acc3b[r4];
      }
    }
    if (ln == sb + 8){
#pragma unroll
      for (int r4 = 0; r4 < 4; ++r4){
        int d0 = wv*32 + lk*4 + r4;
        h3q[d0] = acc3a[r4]; h3q[d0+16] = acc3b[r4];
      }
    }
    __syncthreads();
    if (tid < 128) h3row[tid] = fmaxf(h3p[tid] + h3q[tid] + b3L[tid], 0.0f);
    __syncthreads();
    if (wv == 0){
      const int l = tid, c = l >> 2, kq = l & 3;
      float p = 0.f;
      if (c < 10){
        const float* wr = &W4L[c*130 + kq*32];
        const float* hr = &h3row[kq*32];
#pragma unroll
        for (int k = 0; k < 32; ++k) p += wr[k]*hr[k];
      }
      p += __shfl_xor(p, 1, 4);
      p += __shfl_xor(p, 2, 4);
      if (c < 10 && kq == 0) ytmp[c] = p + b4L[c];
      asm volatile("s_waitcnt lgkmcnt(0)" ::: "memory");
      float yv = (l < 10) ? ytmp[l] : -INFINITY;
      float mx = yv;
#pragma unroll
      for (int off = 1; off < 16; off <<= 1)
        mx = fmaxf(mx, __shfl_xor(mx, off, 16));
      float ex = (l < 10) ? expf(yv - mx) : 0.0f;
      float sm = ex;
#pragma unroll
      for (int off = 1; off < 16; off <<= 1)
        sm += __shfl_xor(sm, off, 16);
      if (l < 10)
        outg[((size_t)(gp*GR + sb)*NT + (NT-1))*NC + l] = yv - (mx + logf(sm));
    }
  }
}

extern "C" void kernel_launch(void* const* d_in, const int* in_sizes, int n_in,
                              void* d_out, int out_size, void* d_ws, size_t ws_size,
                              hipStream_t stream) {
  const float* xg  = (const float*)d_in[0];
  const float* h1i = (const float*)d_in[1];
  const float* h2i = (const float*)d_in[2];
  const float* W1  = (const float*)d_in[3];
  const float* b1  = (const float*)d_in[4];
  const float* W2  = (const float*)d_in[5];
  const float* b2  = (const float*)d_in[6];
  const float* W3  = (const float*)d_in[7];
  const float* b3  = (const float*)d_in[8];
  const float* W4  = (const float*)d_in[9];
  const float* b4  = (const float*)d_in[10];
  float* out = (float*)d_out;
  float* ws  = (float*)d_ws;

  // clear all message epochs (stale epochs from a previous replay would
  // falsely validate): h1buf 1 MiB + h2buf 1 MiB
  hipMemsetAsync(d_ws, 0, 2u * 1024u * 1024u, stream);

  egru_persistent<<<dim3(256), dim3(256), 0, stream>>>(
      xg, h1i, h2i, W1, b1, W2, b2, W3, b3, W4, b4, out, ws);
}